// Round 3
// baseline (1919.945 us; speedup 1.0000x reference)
//
#include <hip/hip_runtime.h>
#include <cfloat>
#include <cmath>

typedef short short8 __attribute__((ext_vector_type(8)));
typedef unsigned short ushort8 __attribute__((ext_vector_type(8)));
typedef float f32x16 __attribute__((ext_vector_type(16)));

#define K_CODES 8192
#define DIM 256
#define NQ_TOTAL 32768
#define CSPLIT 8
#define CT_PER_BLOCK 8   /* 8192 / 128 / CSPLIT */
#define TOPN 8

/* ws layout (byte offsets) */
#define WS_COUNTS 0          /* int[8192]                  32 KB (zeroed) */
#define WS_LOSSQ  32768      /* float[32768]              128 KB */
#define WS_NORMS  163840     /* float[8192]                32 KB */
#define WS_PVAL   196608     /* float[8*32768*8]            8 MB */
#define WS_PIDX   8585216    /* int  [8*32768*8]            8 MB */
#define WS_ET     16973824   /* float[8192*256]             8 MB */
#define WS_AHI    25362432   /* ushort[8192*256]            4 MB */
#define WS_BHI    29556736   /* ushort[32768*256]          16 MB */

__device__ inline unsigned short f32_to_bf16_rne(float x) {
    unsigned u = __builtin_bit_cast(unsigned, x);
    unsigned r = u + 0x7FFFu + ((u >> 16) & 1u);
    return (unsigned short)(r >> 16);
}

// sorted-descending top-N insert with carry-down (caller guards v > tv[N-1])
__device__ inline void insN(float v, int c, float* tv, int* ti) {
#pragma unroll
    for (int j = 0; j < TOPN; ++j) {
        bool g = v > tv[j];
        float ov = tv[j]; int oc = ti[j];
        tv[j] = g ? v : ov;  ti[j] = g ? c : oc;
        v = g ? ov : v;      c = g ? oc : c;
    }
}

// ---------------------------------------------------------------- norms (fp32, exact)
__global__ __launch_bounds__(256) void norms_kernel(const float* __restrict__ E,
                                                    float* __restrict__ norms) {
    int k = blockIdx.x * 256 + threadIdx.x;
    float s = 0.f;
#pragma unroll 8
    for (int d = 0; d < DIM; ++d) { float v = E[(size_t)d * K_CODES + k]; s += v * v; }
    norms[k] = s;
}

// ---------------------------------------------------------------- pack X -> frag-linear bf16
__global__ __launch_bounds__(256) void pack_X(const float* __restrict__ X,
                                              unsigned short* __restrict__ Bhi) {
    int id = blockIdx.x * 256 + threadIdx.x;      // 1048576 total
    int q = id >> 5, db = id & 31;
    const float* src = X + (size_t)q * DIM + db * 8;
    float4 a = *(const float4*)src, b = *(const float4*)(src + 4);
    float xs[8] = {a.x, a.y, a.z, a.w, b.x, b.y, b.z, b.w};
    ushort8 vh;
#pragma unroll
    for (int i = 0; i < 8; ++i) vh[i] = f32_to_bf16_rne(xs[i]);
    int qt = q >> 7, nt = (q >> 5) & 3, lq = q & 31, s = db >> 1, hh = db & 1;
    int lane = lq + 32 * hh;
    size_t chunk = ((((size_t)qt * 16 + s) * 4 + nt) * 64 + lane) * 8;
    *(ushort8*)&Bhi[chunk] = vh;
}

// ---------------------------------------------------------------- pack E -> A frags + fp32 E^T
__global__ __launch_bounds__(256) void pack_E(const float* __restrict__ E,
                                              unsigned short* __restrict__ Ahi,
                                              float* __restrict__ ET) {
    int id = blockIdx.x * 256 + threadIdx.x;      // 262144 total
    int db = id >> 13, c = id & 8191;
    float xs[8];
#pragma unroll
    for (int j = 0; j < 8; ++j) xs[j] = E[(size_t)(db * 8 + j) * K_CODES + c];
    float4 f0 = {xs[0], xs[1], xs[2], xs[3]}, f1 = {xs[4], xs[5], xs[6], xs[7]};
    *(float4*)&ET[(size_t)c * DIM + db * 8]     = f0;
    *(float4*)&ET[(size_t)c * DIM + db * 8 + 4] = f1;
    ushort8 vh;
#pragma unroll
    for (int j = 0; j < 8; ++j) vh[j] = f32_to_bf16_rne(xs[j]);
    int ct = c >> 7, mt = (c >> 5) & 3, lc = c & 31, s = db >> 1, hh = db & 1;
    int lane = lc + 32 * hh;
    size_t chunk = ((((size_t)ct * 16 + s) * 4 + mt) * 64 + lane) * 8;
    *(ushort8*)&Ahi[chunk] = vh;
}

// ---------------------------------------------------------------- MFMA argmax, single bf16 product
// grid (CSPLIT, 256 query-tiles), 256 threads = 4 waves, wave = 64 codes x 64 queries.
// No LDS / no barriers in the K-loop: frags stream global->VGPR, double-buffered.
__global__ __launch_bounds__(256) void argmax_mfma(
        const unsigned short* __restrict__ Ahi, const unsigned short* __restrict__ Bhi,
        const float* __restrict__ norms,
        float* __restrict__ pval, int* __restrict__ pidx) {
    __shared__ float pvs[4][128][TOPN];
    __shared__ int   pis[4][128][TOPN];
    const int tid = threadIdx.x;
    const int lane = tid & 63, w = tid >> 6;
    const int wm = w & 1, wn = w >> 1;
    const int h = lane >> 5;
    const int cs = blockIdx.x, qt = blockIdx.y;

    float tv[2][TOPN]; int ti[2][TOPN];
#pragma unroll
    for (int nt = 0; nt < 2; ++nt)
#pragma unroll
        for (int j = 0; j < TOPN; ++j) { tv[nt][j] = -FLT_MAX; ti[nt][j] = 0; }

    // frag chunk layout: (((tile*16 + ss)*4 + slot)*64 + lane)*8 shorts
    const unsigned short* Bb = Bhi + (((size_t)qt * 64 + wn * 2) * 64 + lane) * 8;

    for (int ctl = 0; ctl < CT_PER_BLOCK; ++ctl) {
        const int ctg = cs * CT_PER_BLOCK + ctl;
        const unsigned short* Ab = Ahi + (((size_t)ctg * 64 + wm * 2) * 64 + lane) * 8;

        f32x16 acc[2][2];
#pragma unroll
        for (int mt = 0; mt < 2; ++mt)
#pragma unroll
            for (int nt = 0; nt < 2; ++nt)
#pragma unroll
                for (int r = 0; r < 16; ++r) acc[mt][nt][r] = 0.f;

        short8 af[2][2], bf2[2][2];          // [buf][mt/nt]
        af[0][0]  = *(const short8*)(Ab);
        af[0][1]  = *(const short8*)(Ab + 512);
        bf2[0][0] = *(const short8*)(Bb);
        bf2[0][1] = *(const short8*)(Bb + 512);
#pragma unroll
        for (int ss = 0; ss < 16; ++ss) {
            const int cb = ss & 1, nb = cb ^ 1;
            if (ss < 15) {                   // prefetch next K=16 step into other buffer
                const int o = (ss + 1) * 2048;
                af[nb][0]  = *(const short8*)(Ab + o);
                af[nb][1]  = *(const short8*)(Ab + o + 512);
                bf2[nb][0] = *(const short8*)(Bb + o);
                bf2[nb][1] = *(const short8*)(Bb + o + 512);
            }
#pragma unroll
            for (int mt = 0; mt < 2; ++mt)
#pragma unroll
                for (int nt = 0; nt < 2; ++nt)
                    acc[mt][nt] = __builtin_amdgcn_mfma_f32_32x32x16_bf16(
                        af[cb][mt], bf2[cb][nt], acc[mt][nt], 0, 0, 0);
        }

        // epilogue: fold exact norms, guarded top-8 insert
        const int cbase = ctg * 128;
#pragma unroll
        for (int mt = 0; mt < 2; ++mt) {
            const int cb0 = cbase + (wm * 2 + mt) * 32 + 4 * h;
#pragma unroll
            for (int r = 0; r < 16; ++r) {
                const int code = cb0 + (r & 3) + 8 * (r >> 2);
                const float nrm = norms[code];
#pragma unroll
                for (int nt = 0; nt < 2; ++nt) {
                    float v = 2.f * acc[mt][nt][r] - nrm;
                    if (v > tv[nt][TOPN - 1]) insN(v, code, tv[nt], ti[nt]);
                }
            }
        }
    }

    // merge 4 partial top-8s per query (wm x h slots) -> ws partials
    const int slot = wm * 2 + h;
#pragma unroll
    for (int nt = 0; nt < 2; ++nt) {
        const int ql = wn * 64 + nt * 32 + (lane & 31);
#pragma unroll
        for (int j = 0; j < TOPN; ++j) { pvs[slot][ql][j] = tv[nt][j]; pis[slot][ql][j] = ti[nt][j]; }
    }
    __syncthreads();
    if (tid < 128) {
        float mv[TOPN]; int mi[TOPN];
#pragma unroll
        for (int j = 0; j < TOPN; ++j) { mv[j] = -FLT_MAX; mi[j] = 0; }
#pragma unroll
        for (int sl = 0; sl < 4; ++sl)
#pragma unroll
            for (int j = 0; j < TOPN; ++j) {
                float v = pvs[sl][tid][j]; int c = pis[sl][tid][j];
                if (v > mv[TOPN - 1]) insN(v, c, mv, mi);
            }
        size_t o = ((size_t)cs * NQ_TOTAL + qt * 128 + tid) * TOPN;
#pragma unroll
        for (int j = 0; j < TOPN; ++j) { pval[o + j] = mv[j]; pidx[o + j] = mi[j]; }
    }
}

// ---------------------------------------------------------------- candidate merge + exact rescore
// one wave per query; 64 candidates (8 slices x top-8) mapped 1:1 to lanes;
// 8 rounds of wave-argmax pick approx top-8; exact fp32 rescore picks the winner.
__global__ __launch_bounds__(256) void finalize_q(
        const float* __restrict__ X, const float* __restrict__ ET,
        const float* __restrict__ norms, const float* __restrict__ pval,
        const int* __restrict__ pidx, float* __restrict__ outq,
        float* __restrict__ out_idx_f, float* __restrict__ loss_q,
        int* __restrict__ counts) {
    const int lane = threadIdx.x & 63, w = threadIdx.x >> 6;
    const int q = blockIdx.x * 4 + w;
    float4 x4 = *(const float4*)&X[(size_t)q * DIM + lane * 4];

    // lane -> candidate (slice p = lane>>3, rank j = lane&7)
    const int p = lane >> 3, j = lane & 7;
    size_t off = ((size_t)p * NQ_TOTAL + q) * TOPN + j;
    float wv = pval[off];
    int   wc = pidx[off];

    int kc[TOPN];
#pragma unroll
    for (int t = 0; t < TOPN; ++t) {
        float v = wv; int src = lane;
#pragma unroll
        for (int o = 1; o < 64; o <<= 1) {
            float ov = __shfl_xor(v, o); int os = __shfl_xor(src, o);
            bool take = (ov > v) || (ov == v && os < src);
            v = take ? ov : v; src = take ? os : src;
        }
        kc[t] = __shfl(wc, src);
        if (lane == src) wv = -FLT_MAX;     // remove winner
    }

    float sb = -FLT_MAX; int kb = 0; float4 eb = x4;
#pragma unroll
    for (int t = 0; t < TOPN; ++t) {
        int k = kc[t];
        float4 e4 = *(const float4*)&ET[(size_t)k * DIM + lane * 4];
        float pr = x4.x * e4.x + x4.y * e4.y + x4.z * e4.z + x4.w * e4.w;
#pragma unroll
        for (int o = 1; o < 64; o <<= 1) pr += __shfl_xor(pr, o);
        float s = 2.f * pr - norms[k];
        bool better = (s > sb) || (s == sb && k < kb);
        if (better) { sb = s; kb = k; eb = e4; }
    }
    float4 d4 = {eb.x - x4.x, eb.y - x4.y, eb.z - x4.z, eb.w - x4.w};
    float4 o4 = {x4.x + d4.x, x4.y + d4.y, x4.z + d4.z, x4.w + d4.w};
    *(float4*)&outq[(size_t)q * DIM + lane * 4] = o4;
    float l = d4.x * d4.x + d4.y * d4.y + d4.z * d4.z + d4.w * d4.w;
#pragma unroll
    for (int o = 1; o < 64; o <<= 1) l += __shfl_xor(l, o);
    if (lane == 0) {
        out_idx_f[q] = (float)kb;
        loss_q[q] = l;
        atomicAdd(&counts[kb], 1);
    }
}

// ---------------------------------------------------------------- scalars
__global__ __launch_bounds__(256) void final_scalars(
        const int* __restrict__ counts, const float* __restrict__ loss_q,
        float* __restrict__ out_sc) {
    int t = threadIdx.x;
    float ls = 0.f;
    for (int i = t; i < NQ_TOTAL; i += 256) ls += loss_q[i];
    float ent = 0.f;
    for (int k = t; k < K_CODES; k += 256) {
        float p = (float)counts[k] / (float)NQ_TOTAL;
        ent -= p * logf(p + 1e-10f);
    }
#pragma unroll
    for (int o = 1; o < 64; o <<= 1) { ls += __shfl_xor(ls, o); ent += __shfl_xor(ent, o); }
    __shared__ float rl[4], re[4];
    if ((t & 63) == 0) { rl[t >> 6] = ls; re[t >> 6] = ent; }
    __syncthreads();
    if (t == 0) {
        float L = rl[0] + rl[1] + rl[2] + rl[3];
        float Ee = re[0] + re[1] + re[2] + re[3];
        float mse = L / (float)((size_t)NQ_TOTAL * DIM);
        out_sc[0] = 1.1f * mse;                         // e_latent + 0.1*q_latent
        out_sc[1] = -0.1f * (Ee / logf((float)K_CODES));
    }
}

extern "C" void kernel_launch(void* const* d_in, const int* in_sizes, int n_in,
                              void* d_out, int out_size, void* d_ws, size_t ws_size,
                              hipStream_t stream) {
    const float* X = (const float*)d_in[0];   // [32768, 256] fp32
    const float* E = (const float*)d_in[1];   // [256, 8192]  fp32

    float* out       = (float*)d_out;
    float* outq      = out;                           // 8388608
    float* out_idx_f = out + (size_t)NQ_TOTAL * DIM;  // 32768 (indices as f32)
    float* out_sc    = out_idx_f + NQ_TOTAL;          // 2 scalars

    char* ws = (char*)d_ws;
    int*            counts = (int*)(ws + WS_COUNTS);
    float*          loss_q = (float*)(ws + WS_LOSSQ);
    float*          norms  = (float*)(ws + WS_NORMS);
    float*          pval   = (float*)(ws + WS_PVAL);
    int*            pidx   = (int*)(ws + WS_PIDX);
    float*          ET     = (float*)(ws + WS_ET);
    unsigned short* Ahi    = (unsigned short*)(ws + WS_AHI);
    unsigned short* Bhi    = (unsigned short*)(ws + WS_BHI);

    hipMemsetAsync(counts, 0, K_CODES * sizeof(int), stream);
    norms_kernel<<<K_CODES / 256, 256, 0, stream>>>(E, norms);
    pack_X<<<(NQ_TOTAL * 32) / 256, 256, 0, stream>>>(X, Bhi);
    pack_E<<<(K_CODES * 32) / 256, 256, 0, stream>>>(E, Ahi, ET);
    argmax_mfma<<<dim3(CSPLIT, NQ_TOTAL / 128), 256, 0, stream>>>(Ahi, Bhi, norms, pval, pidx);
    finalize_q<<<NQ_TOTAL / 4, 256, 0, stream>>>(X, ET, norms, pval, pidx, outq, out_idx_f, loss_q, counts);
    final_scalars<<<1, 256, 0, stream>>>(counts, loss_q, out_sc);
}

// Round 4
// 849.575 us; speedup vs baseline: 2.2599x; 2.2599x over previous
//
#include <hip/hip_runtime.h>
#include <cfloat>
#include <cmath>

typedef short short8 __attribute__((ext_vector_type(8)));
typedef unsigned short ushort8 __attribute__((ext_vector_type(8)));
typedef float f32x16 __attribute__((ext_vector_type(16)));

#define K_CODES 8192
#define DIM 256
#define NQ_TOTAL 32768
#define CSPLIT 8
#define CT2_PER_BLOCK 4   /* 4 x 256-code tiles = 1024 codes per block */
#define TOPN 8

/* ws layout (byte offsets) */
#define WS_COUNTS 0          /* int[8192]                  32 KB (zeroed) */
#define WS_LOSSQ  32768      /* float[32768]              128 KB */
#define WS_NORMS  163840     /* float[8192]                32 KB */
#define WS_PVAL   196608     /* float[8*32768*8]            8 MB */
#define WS_PIDX   8585216    /* int  [8*32768*8]            8 MB */
#define WS_ET     16973824   /* float[8192*256]             8 MB */
#define WS_AHI    25362432   /* ushort[8192*256]            4 MB */
#define WS_BHI    29556736   /* ushort[32768*256]          16 MB */

__device__ inline unsigned short f32_to_bf16_rne(float x) {
    unsigned u = __builtin_bit_cast(unsigned, x);
    unsigned r = u + 0x7FFFu + ((u >> 16) & 1u);
    return (unsigned short)(r >> 16);
}

// sorted-descending top-N insert with carry-down (caller guards v > tv[N-1])
__device__ inline void insN(float v, int c, float* tv, int* ti) {
#pragma unroll
    for (int j = 0; j < TOPN; ++j) {
        bool g = v > tv[j];
        float ov = tv[j]; int oc = ti[j];
        tv[j] = g ? v : ov;  ti[j] = g ? c : oc;
        v = g ? ov : v;      c = g ? oc : c;
    }
}

// ---------------------------------------------------------------- norms (fp32, exact)
__global__ __launch_bounds__(256) void norms_kernel(const float* __restrict__ E,
                                                    float* __restrict__ norms) {
    int k = blockIdx.x * 256 + threadIdx.x;
    float s = 0.f;
#pragma unroll 8
    for (int d = 0; d < DIM; ++d) { float v = E[(size_t)d * K_CODES + k]; s += v * v; }
    norms[k] = s;
}

// ---------------------------------------------------------------- pack X -> frag-linear bf16
__global__ __launch_bounds__(256) void pack_X(const float* __restrict__ X,
                                              unsigned short* __restrict__ Bhi) {
    int id = blockIdx.x * 256 + threadIdx.x;      // 1048576 total
    int q = id >> 5, db = id & 31;
    const float* src = X + (size_t)q * DIM + db * 8;
    float4 a = *(const float4*)src, b = *(const float4*)(src + 4);
    float xs[8] = {a.x, a.y, a.z, a.w, b.x, b.y, b.z, b.w};
    ushort8 vh;
#pragma unroll
    for (int i = 0; i < 8; ++i) vh[i] = f32_to_bf16_rne(xs[i]);
    int qt = q >> 7, nt = (q >> 5) & 3, lq = q & 31, s = db >> 1, hh = db & 1;
    int lane = lq + 32 * hh;
    size_t chunk = ((((size_t)qt * 16 + s) * 4 + nt) * 64 + lane) * 8;
    *(ushort8*)&Bhi[chunk] = vh;
}

// ---------------------------------------------------------------- pack E -> A frags + fp32 E^T
__global__ __launch_bounds__(256) void pack_E(const float* __restrict__ E,
                                              unsigned short* __restrict__ Ahi,
                                              float* __restrict__ ET) {
    int id = blockIdx.x * 256 + threadIdx.x;      // 262144 total
    int db = id >> 13, c = id & 8191;
    float xs[8];
#pragma unroll
    for (int j = 0; j < 8; ++j) xs[j] = E[(size_t)(db * 8 + j) * K_CODES + c];
    float4 f0 = {xs[0], xs[1], xs[2], xs[3]}, f1 = {xs[4], xs[5], xs[6], xs[7]};
    *(float4*)&ET[(size_t)c * DIM + db * 8]     = f0;
    *(float4*)&ET[(size_t)c * DIM + db * 8 + 4] = f1;
    ushort8 vh;
#pragma unroll
    for (int j = 0; j < 8; ++j) vh[j] = f32_to_bf16_rne(xs[j]);
    int ct = c >> 7, mt = (c >> 5) & 3, lc = c & 31, s = db >> 1, hh = db & 1;
    int lane = lc + 32 * hh;
    size_t chunk = ((((size_t)ct * 16 + s) * 4 + mt) * 64 + lane) * 8;
    *(ushort8*)&Ahi[chunk] = vh;
}

// ---------------------------------------------------------------- MFMA argmax (single bf16 product)
// grid (CSPLIT, 256 query-tiles), 256 threads = 4 waves.
// Block tile: 256 codes x 128 queries; wave tile 128 codes x 64 queries (4x2 acc of 32x32).
// K-loop: global_load_lds DMA staging (24 KB/stage), 2-barrier structure (r2-proven).
__global__ __launch_bounds__(256, 2) void argmax_mfma(
        const unsigned short* __restrict__ Ahi, const unsigned short* __restrict__ Bhi,
        const float* __restrict__ norms,
        float* __restrict__ pval, int* __restrict__ pidx) {
    __shared__ __align__(16) char smem[32768];     // stage (24KB) unioned with merge (32KB)
    unsigned short* sst = (unsigned short*)smem;
    float (*pvs)[128][TOPN] = (float (*)[128][TOPN])smem;
    int   (*pis)[128][TOPN] = (int (*)[128][TOPN])(smem + 16384);

    const int tid = threadIdx.x;
    const int lane = tid & 63, w = tid >> 6;
    const int wm = w & 1, wn = w >> 1;             // wave -> (code 128-half, query 64-half)
    const int h = lane >> 5;
    const int cs = blockIdx.x, qt = blockIdx.y;

    float tv[2][TOPN]; int ti[2][TOPN];
#pragma unroll
    for (int n2 = 0; n2 < 2; ++n2)
#pragma unroll
        for (int j = 0; j < TOPN; ++j) { tv[n2][j] = -FLT_MAX; ti[n2][j] = 0; }

    for (int ctl = 0; ctl < CT2_PER_BLOCK; ++ctl) {
        const int ctb = cs * (CT2_PER_BLOCK * 2) + ctl * 2;   // base 128-code tile index

        f32x16 acc[4][2];
#pragma unroll
        for (int mt = 0; mt < 4; ++mt)
#pragma unroll
            for (int n2 = 0; n2 < 2; ++n2)
#pragma unroll
                for (int r = 0; r < 16; ++r) acc[mt][n2][r] = 0.f;

        for (int st = 0; st < 8; ++st) {           // D-loop: 8 stages x BK=32
            const int st2 = st * 2;
            __syncthreads();                       // previous stage's readers done
#pragma unroll
            for (int i = 0; i < 6; ++i) {          // 24 x 1KB wave-chunks, 24KB/stage
                const int g = w * 6 + i;
                const unsigned short* src;
                int dst;
                if (g < 16) {                      // A: [c2][s2][mt]
                    const int s2 = g & 1, mt = (g >> 1) & 3, c2 = g >> 3;
                    src = Ahi + ((((size_t)(ctb + c2) * 16 + st2 + s2) * 4 + mt) * 64 + lane) * 8;
                    dst = ((c2 * 2 + s2) * 4 + mt) * 512;
                } else {                           // B: [s2][nt]
                    const int gg = g - 16, s2 = gg & 1, nt = (gg >> 1) & 3;
                    src = Bhi + ((((size_t)qt * 16 + st2 + s2) * 4 + nt) * 64 + lane) * 8;
                    dst = 8192 + (s2 * 4 + nt) * 512;
                }
                __builtin_amdgcn_global_load_lds(
                    (const __attribute__((address_space(1))) unsigned int*)src,
                    (__attribute__((address_space(3))) unsigned int*)(sst + dst), 16, 0, 0);
            }
            __syncthreads();                       // vmcnt drained -> LDS visible
#pragma unroll
            for (int ss2 = 0; ss2 < 2; ++ss2) {
                short8 af[4], bf[2];
#pragma unroll
                for (int mt = 0; mt < 4; ++mt)
                    af[mt] = *(const short8*)&sst[((wm * 2 + ss2) * 4 + mt) * 512 + lane * 8];
#pragma unroll
                for (int n2 = 0; n2 < 2; ++n2)
                    bf[n2] = *(const short8*)&sst[8192 + (ss2 * 4 + wn * 2 + n2) * 512 + lane * 8];
#pragma unroll
                for (int mt = 0; mt < 4; ++mt)
#pragma unroll
                    for (int n2 = 0; n2 < 2; ++n2)
                        acc[mt][n2] = __builtin_amdgcn_mfma_f32_32x32x16_bf16(
                            af[mt], bf[n2], acc[mt][n2], 0, 0, 0);
            }
        }

        // epilogue: fold exact norms, guarded top-8 insert (codes ascending)
        const int cbase = (ctb + wm) * 128;
#pragma unroll
        for (int mt = 0; mt < 4; ++mt) {
            const int cb0 = cbase + mt * 32 + 4 * h;
#pragma unroll
            for (int r = 0; r < 16; ++r) {
                const int code = cb0 + (r & 3) + 8 * (r >> 2);
                const float nrm = norms[code];
#pragma unroll
                for (int n2 = 0; n2 < 2; ++n2) {
                    float v = 2.f * acc[mt][n2][r] - nrm;
                    if (v > tv[n2][TOPN - 1]) insN(v, code, tv[n2], ti[n2]);
                }
            }
        }
    }

    __syncthreads();                               // all LDS stage-reads done before aliasing
    const int slot = wm * 2 + h;
#pragma unroll
    for (int n2 = 0; n2 < 2; ++n2) {
        const int ql = wn * 64 + n2 * 32 + (lane & 31);
#pragma unroll
        for (int j = 0; j < TOPN; ++j) { pvs[slot][ql][j] = tv[n2][j]; pis[slot][ql][j] = ti[n2][j]; }
    }
    __syncthreads();
    if (tid < 128) {
        float mv[TOPN]; int mi[TOPN];
#pragma unroll
        for (int j = 0; j < TOPN; ++j) { mv[j] = -FLT_MAX; mi[j] = 0; }
#pragma unroll
        for (int sl = 0; sl < 4; ++sl)
#pragma unroll
            for (int j = 0; j < TOPN; ++j) {
                float v = pvs[sl][tid][j]; int c = pis[sl][tid][j];
                if (v > mv[TOPN - 1]) insN(v, c, mv, mi);
            }
        size_t o = ((size_t)cs * NQ_TOTAL + qt * 128 + tid) * TOPN;
#pragma unroll
        for (int j = 0; j < TOPN; ++j) { pval[o + j] = mv[j]; pidx[o + j] = mi[j]; }
    }
}

// ---------------------------------------------------------------- candidate merge + exact rescore
// one wave per query; 64 candidates (8 slices x top-8) mapped 1:1 to lanes;
// 8 rounds of wave-argmax pick approx top-8; exact fp32 rescore picks the winner.
__global__ __launch_bounds__(256) void finalize_q(
        const float* __restrict__ X, const float* __restrict__ ET,
        const float* __restrict__ norms, const float* __restrict__ pval,
        const int* __restrict__ pidx, float* __restrict__ outq,
        float* __restrict__ out_idx_f, float* __restrict__ loss_q,
        int* __restrict__ counts) {
    const int lane = threadIdx.x & 63, w = threadIdx.x >> 6;
    const int q = blockIdx.x * 4 + w;
    float4 x4 = *(const float4*)&X[(size_t)q * DIM + lane * 4];

    // lane -> candidate (slice p = lane>>3, rank j = lane&7)
    const int p = lane >> 3, j = lane & 7;
    size_t off = ((size_t)p * NQ_TOTAL + q) * TOPN + j;
    float wv = pval[off];
    int   wc = pidx[off];

    int kc[TOPN];
#pragma unroll
    for (int t = 0; t < TOPN; ++t) {
        float v = wv; int src = lane;
#pragma unroll
        for (int o = 1; o < 64; o <<= 1) {
            float ov = __shfl_xor(v, o); int os = __shfl_xor(src, o);
            bool take = (ov > v) || (ov == v && os < src);
            v = take ? ov : v; src = take ? os : src;
        }
        kc[t] = __shfl(wc, src);
        if (lane == src) wv = -FLT_MAX;     // remove winner
    }

    float sb = -FLT_MAX; int kb = 0; float4 eb = x4;
#pragma unroll
    for (int t = 0; t < TOPN; ++t) {
        int k = kc[t];
        float4 e4 = *(const float4*)&ET[(size_t)k * DIM + lane * 4];
        float pr = x4.x * e4.x + x4.y * e4.y + x4.z * e4.z + x4.w * e4.w;
#pragma unroll
        for (int o = 1; o < 64; o <<= 1) pr += __shfl_xor(pr, o);
        float s = 2.f * pr - norms[k];
        bool better = (s > sb) || (s == sb && k < kb);
        if (better) { sb = s; kb = k; eb = e4; }
    }
    float4 d4 = {eb.x - x4.x, eb.y - x4.y, eb.z - x4.z, eb.w - x4.w};
    float4 o4 = {x4.x + d4.x, x4.y + d4.y, x4.z + d4.z, x4.w + d4.w};
    *(float4*)&outq[(size_t)q * DIM + lane * 4] = o4;
    float l = d4.x * d4.x + d4.y * d4.y + d4.z * d4.z + d4.w * d4.w;
#pragma unroll
    for (int o = 1; o < 64; o <<= 1) l += __shfl_xor(l, o);
    if (lane == 0) {
        out_idx_f[q] = (float)kb;
        loss_q[q] = l;
        atomicAdd(&counts[kb], 1);
    }
}

// ---------------------------------------------------------------- scalars
__global__ __launch_bounds__(256) void final_scalars(
        const int* __restrict__ counts, const float* __restrict__ loss_q,
        float* __restrict__ out_sc) {
    int t = threadIdx.x;
    float ls = 0.f;
    for (int i = t; i < NQ_TOTAL; i += 256) ls += loss_q[i];
    float ent = 0.f;
    for (int k = t; k < K_CODES; k += 256) {
        float p = (float)counts[k] / (float)NQ_TOTAL;
        ent -= p * logf(p + 1e-10f);
    }
#pragma unroll
    for (int o = 1; o < 64; o <<= 1) { ls += __shfl_xor(ls, o); ent += __shfl_xor(ent, o); }
    __shared__ float rl[4], re[4];
    if ((t & 63) == 0) { rl[t >> 6] = ls; re[t >> 6] = ent; }
    __syncthreads();
    if (t == 0) {
        float L = rl[0] + rl[1] + rl[2] + rl[3];
        float Ee = re[0] + re[1] + re[2] + re[3];
        float mse = L / (float)((size_t)NQ_TOTAL * DIM);
        out_sc[0] = 1.1f * mse;                         // e_latent + 0.1*q_latent
        out_sc[1] = -0.1f * (Ee / logf((float)K_CODES));
    }
}

extern "C" void kernel_launch(void* const* d_in, const int* in_sizes, int n_in,
                              void* d_out, int out_size, void* d_ws, size_t ws_size,
                              hipStream_t stream) {
    const float* X = (const float*)d_in[0];   // [32768, 256] fp32
    const float* E = (const float*)d_in[1];   // [256, 8192]  fp32

    float* out       = (float*)d_out;
    float* outq      = out;                           // 8388608
    float* out_idx_f = out + (size_t)NQ_TOTAL * DIM;  // 32768 (indices as f32)
    float* out_sc    = out_idx_f + NQ_TOTAL;          // 2 scalars

    char* ws = (char*)d_ws;
    int*            counts = (int*)(ws + WS_COUNTS);
    float*          loss_q = (float*)(ws + WS_LOSSQ);
    float*          norms  = (float*)(ws + WS_NORMS);
    float*          pval   = (float*)(ws + WS_PVAL);
    int*            pidx   = (int*)(ws + WS_PIDX);
    float*          ET     = (float*)(ws + WS_ET);
    unsigned short* Ahi    = (unsigned short*)(ws + WS_AHI);
    unsigned short* Bhi    = (unsigned short*)(ws + WS_BHI);

    hipMemsetAsync(counts, 0, K_CODES * sizeof(int), stream);
    norms_kernel<<<K_CODES / 256, 256, 0, stream>>>(E, norms);
    pack_X<<<(NQ_TOTAL * 32) / 256, 256, 0, stream>>>(X, Bhi);
    pack_E<<<(K_CODES * 32) / 256, 256, 0, stream>>>(E, Ahi, ET);
    argmax_mfma<<<dim3(CSPLIT, NQ_TOTAL / 128), 256, 0, stream>>>(Ahi, Bhi, norms, pval, pidx);
    finalize_q<<<NQ_TOTAL / 4, 256, 0, stream>>>(X, ET, norms, pval, pidx, outq, out_idx_f, loss_q, counts);
    final_scalars<<<1, 256, 0, stream>>>(counts, loss_q, out_sc);
}